// Round 2
// baseline (6278.123 us; speedup 1.0000x reference)
//
#include <hip/hip_runtime.h>
#include <math.h>

typedef unsigned long long u64;

#define NPROP 1000
#define KDIM 25088
#define HDIM 1024
#define NBOX 20000      // 1000 * 20
#define NPAD 20480      // 10 runs of 2048
#define KPRE 2000
#define LOGC 4.135166556742356f
#define BK 16

// order-preserving float->uint map (ascending)
__device__ inline unsigned ordkey(float f) {
    unsigned u = __float_as_uint(f);
    return (u & 0x80000000u) ? ~u : (u | 0x80000000u);
}
// key sorts ASCENDING == score DESCENDING, ties: lower index first (lax.top_k semantics)
__device__ inline u64 mkkey(float s, unsigned i) {
    return ((u64)(unsigned)(~ordkey(s)) << 32) | (u64)i;
}

// ---------------- ROI pool ----------------
__global__ void roi_pool_kernel(const float* __restrict__ feat, const float* __restrict__ props,
                                float* __restrict__ pooled)
{
    __shared__ int xi[14], yi[14];
    int n = blockIdx.x;
    int tid = threadIdx.x;
    if (tid < 28) {
        bool isx = tid < 14;
        int k = isx ? tid : tid - 14;
        float lo = props[n*4 + (isx ? 0 : 1)] * 0.0625f;
        float hi = props[n*4 + (isx ? 2 : 3)] * 0.0625f;
        float bsz = (hi - lo) / 7.0f;
        float g = ((float)k + 0.5f) * 0.5f;
        float gv = __fadd_rn(lo, __fmul_rn(g, bsz));
        int v = (int)floorf(gv);
        v = v < 0 ? 0 : (v > 49 ? 49 : v);
        if (isx) xi[k] = v; else yi[k] = v;
    }
    __syncthreads();
    for (int o = tid; o < KDIM; o += 256) {
        int c = o / 49;
        int p = o - c * 49;
        int py = p / 7, px = p - py * 7;
        const float* fc = feat + (size_t)c * 2500;
        int y0 = yi[2*py] * 50, y1 = yi[2*py+1] * 50;
        int x0 = xi[2*px],      x1 = xi[2*px+1];
        float v = fmaxf(fmaxf(fc[y0+x0], fc[y0+x1]), fmaxf(fc[y1+x0], fc[y1+x1]));
        pooled[(size_t)n * KDIM + o] = v;
    }
}

// ---------------- split-K fp32 GEMM, tile 128Mx256N, BK=16, 16x8 micro, dbuf LDS ----------------
// grid (Mtiles, Ntiles=4, Sk); block 256. N fixed 1024.
__global__ __launch_bounds__(256, 2)
void gemm_splitk(const float* __restrict__ A, const float* __restrict__ B,
                 float* __restrict__ P, int Mreal, int lda, int Kseg)
{
    __shared__ float As[2][BK][128];   // [k][chunk-transposed m]
    __shared__ float Bs[2][BK][256];
    const int bm = blockIdx.x * 128;
    const int bn = blockIdx.y * 256;
    const int s  = blockIdx.z;
    const int k0 = s * Kseg;
    const int tid = threadIdx.x;
    const int w = tid >> 6, lane = tid & 63;
    const int lr = lane >> 3, lc = lane & 7;
    const int c0 = w * 64 + lc * 8;          // col in tile
    const int m0 = lr * 16;                  // row base in tile

    // staging
    const int ar = tid >> 1, aq = (tid & 1) * 8;       // A: row ar, 8 consecutive k
    const int bkr = tid >> 4, bnc = (tid & 15) * 16;   // B: k-row, 16 cols
    // chunk-transposed float offset for A row ar: m = lr16*16 + q*4 + e -> (q*8+lr16)*4+e
    const int afo = ((((ar >> 2) & 3) << 3) + (ar >> 4)) * 4 + (ar & 3);

    const bool arok = (bm + ar) < Mreal;
    const float* Ap = A + (size_t)(bm + ar) * lda + k0 + aq;
    const float* Bp = B + (size_t)(k0 + bkr) * 1024 + bn + bnc;

    float acc[16][8];
    #pragma unroll
    for (int i = 0; i < 16; ++i)
        #pragma unroll
        for (int j = 0; j < 8; ++j) acc[i][j] = 0.f;

    float4 a0, a1, b0, b1, b2, b3;
    a0 = a1 = make_float4(0.f,0.f,0.f,0.f);
    if (arok) { a0 = *(const float4*)Ap; a1 = *(const float4*)(Ap + 4); }
    b0 = *(const float4*)Bp; b1 = *(const float4*)(Bp + 4);
    b2 = *(const float4*)(Bp + 8); b3 = *(const float4*)(Bp + 12);

    int nt = Kseg / BK;
    int cur = 0;
    // write prologue -> buf 0
    {
        As[0][aq+0][afo] = a0.x; As[0][aq+1][afo] = a0.y; As[0][aq+2][afo] = a0.z; As[0][aq+3][afo] = a0.w;
        As[0][aq+4][afo] = a1.x; As[0][aq+5][afo] = a1.y; As[0][aq+6][afo] = a1.z; As[0][aq+7][afo] = a1.w;
        *(float4*)&Bs[0][bkr][bnc+0]  = b0; *(float4*)&Bs[0][bkr][bnc+4]  = b1;
        *(float4*)&Bs[0][bkr][bnc+8]  = b2; *(float4*)&Bs[0][bkr][bnc+12] = b3;
    }
    for (int t = 0; t < nt; ++t) {
        if (t + 1 < nt) {
            Ap += BK; Bp += (size_t)BK * 1024;
            a0 = a1 = make_float4(0.f,0.f,0.f,0.f);
            if (arok) { a0 = *(const float4*)Ap; a1 = *(const float4*)(Ap + 4); }
            b0 = *(const float4*)Bp; b1 = *(const float4*)(Bp + 4);
            b2 = *(const float4*)(Bp + 8); b3 = *(const float4*)(Bp + 12);
        }
        __syncthreads();
        #pragma unroll
        for (int kk = 0; kk < BK; ++kk) {
            float a[16], b[8];
            *(float4*)&a[0]  = *(const float4*)&As[cur][kk][(0*8 + lr) * 4];
            *(float4*)&a[4]  = *(const float4*)&As[cur][kk][(1*8 + lr) * 4];
            *(float4*)&a[8]  = *(const float4*)&As[cur][kk][(2*8 + lr) * 4];
            *(float4*)&a[12] = *(const float4*)&As[cur][kk][(3*8 + lr) * 4];
            *(float4*)&b[0] = *(const float4*)&Bs[cur][kk][c0];
            *(float4*)&b[4] = *(const float4*)&Bs[cur][kk][c0 + 4];
            #pragma unroll
            for (int i = 0; i < 16; ++i)
                #pragma unroll
                for (int j = 0; j < 8; ++j)
                    acc[i][j] = fmaf(a[i], b[j], acc[i][j]);
        }
        if (t + 1 < nt) {
            int nxt = cur ^ 1;
            As[nxt][aq+0][afo] = a0.x; As[nxt][aq+1][afo] = a0.y; As[nxt][aq+2][afo] = a0.z; As[nxt][aq+3][afo] = a0.w;
            As[nxt][aq+4][afo] = a1.x; As[nxt][aq+5][afo] = a1.y; As[nxt][aq+6][afo] = a1.z; As[nxt][aq+7][afo] = a1.w;
            *(float4*)&Bs[nxt][bkr][bnc+0]  = b0; *(float4*)&Bs[nxt][bkr][bnc+4]  = b1;
            *(float4*)&Bs[nxt][bkr][bnc+8]  = b2; *(float4*)&Bs[nxt][bkr][bnc+12] = b3;
        }
        cur ^= 1;
    }
    float* Pp = P + ((size_t)s << 20) + (size_t)(bm + m0) * 1024 + bn + c0;
    #pragma unroll
    for (int i = 0; i < 16; ++i) {
        *(float4*)(Pp)     = make_float4(acc[i][0], acc[i][1], acc[i][2], acc[i][3]);
        *(float4*)(Pp + 4) = make_float4(acc[i][4], acc[i][5], acc[i][6], acc[i][7]);
        Pp += 1024;
    }
}

// partial sums -> bias + relu (deterministic order)
__global__ void reduce_bias_relu(const float* __restrict__ P, const float* __restrict__ bias,
                                 float* __restrict__ outp, int S)
{
    int t = blockIdx.x * 256 + threadIdx.x;
    if (t >= NPROP * HDIM) return;
    int m = t >> 10, n = t & 1023;
    float s = bias[n];
    for (int i = 0; i < S; ++i) s += P[((size_t)i << 20) + ((size_t)m << 10) + n];
    outp[(size_t)m * HDIM + n] = fmaxf(s, 0.f);
}

// ---------------- heads: h7(1000x1024) @ w_cls + w_reg ----------------
__global__ void heads_kernel(const float* __restrict__ h7,
                             const float* __restrict__ wc, const float* __restrict__ bc,
                             const float* __restrict__ wr, const float* __restrict__ br,
                             float* __restrict__ cls, float* __restrict__ reg)
{
    __shared__ float hs[HDIM];
    __shared__ float part[128];
    int n = blockIdx.x, tid = threadIdx.x;
    for (int t = tid; t < HDIM; t += 256) hs[t] = h7[(size_t)n * HDIM + t];
    __syncthreads();
    int half = tid >> 7, t = tid & 127;
    float s0 = 0.f, s1 = 0.f, s2 = 0.f, s3 = 0.f;
    if (t < 105) {
        int stride = (t < 21) ? 21 : 84;
        const float* wp = (t < 21) ? (wc + t) : (wr + (t - 21));
        int k0 = half << 9;
        for (int k = k0; k < k0 + 512; k += 4) {
            s0 = fmaf(hs[k+0], wp[(k+0)*stride], s0);
            s1 = fmaf(hs[k+1], wp[(k+1)*stride], s1);
            s2 = fmaf(hs[k+2], wp[(k+2)*stride], s2);
            s3 = fmaf(hs[k+3], wp[(k+3)*stride], s3);
        }
    }
    float s = (s0 + s1) + (s2 + s3);
    if (half && t < 105) part[t] = s;
    __syncthreads();
    if (!half && t < 105) {
        s += part[t];
        if (t < 21) cls[n*21 + t] = s + bc[t];
        else        reg[n*84 + (t - 21)] = s + br[t - 21];
    }
}

// ---------------- softmax + decode + key build (+ padding keys) ----------------
__global__ void decode_kernel(const float* __restrict__ cls, const float* __restrict__ reg,
                              const float* __restrict__ props,
                              float* __restrict__ boxes_all, float* __restrict__ scores_all,
                              u64* __restrict__ keys)
{
    int n = blockIdx.x * 256 + threadIdx.x;
    if (n < NPAD - NBOX) keys[NBOX + n] = ~0ull;   // pad 480 keys
    if (n >= NPROP) return;
    float lg[21];
    float m = -3.4e38f;
    #pragma unroll
    for (int c = 0; c < 21; ++c) { lg[c] = cls[n*21 + c]; m = fmaxf(m, lg[c]); }
    float sum = 0.f;
    #pragma unroll
    for (int c = 0; c < 21; ++c) { lg[c] = expf(lg[c] - m); sum += lg[c]; }
    float p0 = props[n*4+0], p1 = props[n*4+1], p2 = props[n*4+2], p3 = props[n*4+3];
    float w = p2 - p0, h = p3 - p1;
    float cx = __fadd_rn(p0, __fmul_rn(0.5f, w));
    float cy = __fadd_rn(p1, __fmul_rn(0.5f, h));
    for (int c = 1; c < 21; ++c) {
        const float* r = reg + n*84 + c*4;
        float dx = r[0], dy = r[1];
        float dw = fminf(r[2], LOGC);
        float dh = fminf(r[3], LOGC);
        float pcx = __fadd_rn(__fmul_rn(dx, w), cx);
        float pcy = __fadd_rn(__fmul_rn(dy, h), cy);
        float pw = __fmul_rn(expf(dw), w);
        float ph = __fmul_rn(expf(dh), h);
        float x1 = __fsub_rn(pcx, __fmul_rn(0.5f, pw));
        float y1 = __fsub_rn(pcy, __fmul_rn(0.5f, ph));
        float x2 = __fadd_rn(pcx, __fmul_rn(0.5f, pw));
        float y2 = __fadd_rn(pcy, __fmul_rn(0.5f, ph));
        x1 = fminf(fmaxf(x1, 0.f), 800.f); y1 = fminf(fmaxf(y1, 0.f), 800.f);
        x2 = fminf(fmaxf(x2, 0.f), 800.f); y2 = fminf(fmaxf(y2, 0.f), 800.f);
        int i = n*20 + (c - 1);
        float sc = lg[c] / sum;
        boxes_all[i*4+0] = x1; boxes_all[i*4+1] = y1;
        boxes_all[i*4+2] = x2; boxes_all[i*4+3] = y2;
        scores_all[i] = sc;
        keys[i] = mkkey(sc, (unsigned)i);
    }
}

// ---------------- bitonic sort of one 2048 run (ascending), pair-per-thread ----------------
__global__ void sort_runs(u64* keys)
{
    __shared__ u64 sk[2048];
    int tid = threadIdx.x;   // 1024
    u64* base = keys + (size_t)blockIdx.x * 2048;
    sk[tid] = base[tid]; sk[tid + 1024] = base[tid + 1024];
    for (int k = 2; k <= 2048; k <<= 1)
        for (int j = k >> 1; j > 0; j >>= 1) {
            __syncthreads();
            int idx = ((tid & ~(j - 1)) << 1) | (tid & (j - 1));
            int ixj = idx | j;
            u64 a = sk[idx], b = sk[ixj];
            bool up = (idx & k) == 0;
            if ((a > b) == up) { sk[idx] = b; sk[ixj] = a; }
        }
    __syncthreads();
    base[tid] = sk[tid]; base[tid + 1024] = sk[tid + 1024];
}

// ---------------- single-block: merge 10 sorted runs -> top-2048 sorted; fused NMS prep ----------------
__global__ void merge_all(const u64* __restrict__ keys, const float* __restrict__ scores_all,
                          const float* __restrict__ boxes_all, float* __restrict__ tops,
                          float* __restrict__ bx, int* __restrict__ lab, float* __restrict__ obx)
{
    __shared__ u64 T[2048], R[2048];
    int tid = threadIdx.x;  // 1024
    T[tid] = keys[tid]; T[tid + 1024] = keys[tid + 1024];
    for (int r = 1; r < 10; ++r) {
        R[tid] = keys[(size_t)r * 2048 + tid];
        R[tid + 1024] = keys[(size_t)r * 2048 + tid + 1024];
        __syncthreads();
        u64 x0 = T[tid],        y0 = R[2047 - tid];
        u64 x1 = T[tid + 1024], y1 = R[1023 - tid];
        T[tid]        = x0 < y0 ? x0 : y0;
        T[tid + 1024] = x1 < y1 ? x1 : y1;
        for (int j = 1024; j > 0; j >>= 1) {
            __syncthreads();
            int idx = ((tid & ~(j - 1)) << 1) | (tid & (j - 1));
            int ixj = idx | j;
            u64 a = T[idx], b = T[ixj];
            if (a > b) { T[idx] = b; T[ixj] = a; }
        }
        __syncthreads();
    }
    // prep top-2000
    for (int rep = 0; rep < 2; ++rep) {
        int i = rep * 1024 + tid;
        if (i < KPRE) {
            u64 k = T[i];
            unsigned idx = (unsigned)(k & 0xffffffffull);
            tops[i] = scores_all[idx];
            float4 b = *(const float4*)(boxes_all + (size_t)idx * 4);
            *(float4*)(bx + (size_t)i * 4) = b;
            int l = (int)(idx % 20u) + 1;
            lab[i] = l;
            float off = (float)l * 10000.f;
            *(float4*)(obx + (size_t)i * 4) = make_float4(b.x + off, b.y + off, b.z + off, b.w + off);
        }
    }
}

// suppression bitmask
__global__ void iou_mask(const float* __restrict__ obx, u64* __restrict__ mask)
{
    int i = blockIdx.x;
    int lane = threadIdx.x;
    const float4 bi = *(const float4*)(obx + (size_t)i * 4);
    float a1 = __fmul_rn(bi.z - bi.x, bi.w - bi.y);
    for (int w = 0; w < 32; ++w) {
        int j = (w << 6) + lane;
        bool supp = false;
        if (j > i && j < KPRE) {
            float4 bj = *(const float4*)(obx + (size_t)j * 4);
            float a2 = __fmul_rn(bj.z - bj.x, bj.w - bj.y);
            float xl = fmaxf(bi.x, bj.x), yt = fmaxf(bi.y, bj.y);
            float xr = fminf(bi.z, bj.z), yb = fminf(bi.w, bj.w);
            float inter = __fmul_rn(fmaxf(xr - xl, 0.f), fmaxf(yb - yt, 0.f));
            float uni = __fsub_rn(__fadd_rn(a1, a2), inter);
            float iou = inter / uni;
            supp = !(iou <= 0.3f);
        }
        u64 word = __ballot((int)supp);
        if (lane == 0) mask[(size_t)i * 32 + w] = word;
    }
}

// single-wave sequential NMS scan
__global__ void nms_scan_kernel(const u64* __restrict__ mask, const float* __restrict__ tops,
                                float* __restrict__ fsc, u64* __restrict__ keys2)
{
    int lane = threadIdx.x;
    u64 removed = 0;
    if (lane < 32) {
        int base = lane * 64;
        for (int b = 0; b < 64; ++b) {
            int i = base + b;
            float s = (i < KPRE) ? tops[i] : -1.0f;
            if (!(s > 0.05f)) removed |= (1ull << b);
        }
    }
    bool ld = lane < 32;
#define LR(i) ((ld && (i) < KPRE) ? mask[(size_t)(i) * 32 + lane] : 0ull)
    u64 p0=LR(0),p1=LR(1),p2=LR(2),p3=LR(3),p4=LR(4),p5=LR(5),p6=LR(6),p7=LR(7);
    for (int i = 0; i < KPRE; i += 8) {
        u64 n0=LR(i+8),n1=LR(i+9),n2=LR(i+10),n3=LR(i+11),n4=LR(i+12),n5=LR(i+13),n6=LR(i+14),n7=LR(i+15);
#define PROC(ii, pr) { u64 rw = __shfl(removed, (ii) >> 6); if (!((rw >> ((ii) & 63)) & 1ull)) removed |= pr; }
        PROC(i+0, p0) PROC(i+1, p1) PROC(i+2, p2) PROC(i+3, p3)
        PROC(i+4, p4) PROC(i+5, p5) PROC(i+6, p6) PROC(i+7, p7)
        p0=n0;p1=n1;p2=n2;p3=n3;p4=n4;p5=n5;p6=n6;p7=n7;
    }
#undef PROC
#undef LR
    for (int kk = 0; kk < 32; ++kk) {
        int t = (kk << 6) + lane;
        u64 rw = __shfl(removed, kk);
        if (t < KPRE) {
            float s = ((rw >> lane) & 1ull) ? -1.0f : tops[t];
            fsc[t] = s;
            keys2[t] = mkkey(s, (unsigned)t);
        } else {
            keys2[t] = ~0ull;
        }
    }
}

// sort 2048 final keys (pair-per-thread), emit top-100
__global__ void final_sort_out(const u64* __restrict__ keys2, const float* __restrict__ fsc,
                               const float* __restrict__ bx, const int* __restrict__ lab,
                               float* __restrict__ outp)
{
    __shared__ u64 sk[2048];
    int tid = threadIdx.x;  // 1024
    sk[tid] = keys2[tid]; sk[tid + 1024] = keys2[tid + 1024];
    for (int k = 2; k <= 2048; k <<= 1)
        for (int j = k >> 1; j > 0; j >>= 1) {
            __syncthreads();
            int idx = ((tid & ~(j - 1)) << 1) | (tid & (j - 1));
            int ixj = idx | j;
            u64 a = sk[idx], b = sk[ixj];
            bool up = (idx & k) == 0;
            if ((a > b) == up) { sk[idx] = b; sk[ixj] = a; }
        }
    __syncthreads();
    if (tid < 100) {
        u64 key = sk[tid];
        unsigned i2 = (unsigned)(key & 0xffffffffull);
        float4 b4 = *(const float4*)(bx + (size_t)i2 * 4);
        outp[tid*4+0] = b4.x; outp[tid*4+1] = b4.y; outp[tid*4+2] = b4.z; outp[tid*4+3] = b4.w;
        outp[400 + tid] = fsc[i2];
        outp[500 + tid] = (float)lab[i2];
    }
}

extern "C" void kernel_launch(void* const* d_in, const int* in_sizes, int n_in,
                              void* d_out, int out_size, void* d_ws, size_t ws_size,
                              hipStream_t stream)
{
    const float* feat  = (const float*)d_in[0];
    const float* props = (const float*)d_in[1];
    const float* w6    = (const float*)d_in[2];
    const float* b6    = (const float*)d_in[3];
    const float* w7    = (const float*)d_in[4];
    const float* b7    = (const float*)d_in[5];
    const float* wcls  = (const float*)d_in[6];
    const float* bcls  = (const float*)d_in[7];
    const float* wreg  = (const float*)d_in[8];
    const float* breg  = (const float*)d_in[9];
    float* outp = (float*)d_out;

    char* w = (char*)d_ws;
    size_t off = 0;
    auto take = [&](size_t bytes) -> char* {
        char* p = w + off;
        off = (off + bytes + 255) & ~(size_t)255;
        return p;
    };
    float* pooled = (float*)take((size_t)NPROP * KDIM * 4);          // 100.4 MB
    int S6 = (ws_size >= off + 16ull * (1u << 22) + (14ull << 20)) ? 16 : 4;
    float* partial = (float*)take((size_t)S6 * (1u << 22));
    float* h6  = (float*)take(4ull << 20);
    float* h7  = (float*)take(4ull << 20);
    float* cls = (float*)take((size_t)NPROP * 21 * 4);
    float* reg = (float*)take((size_t)NPROP * 84 * 4);
    float* boxes_all  = (float*)take((size_t)NBOX * 16);
    float* scores_all = (float*)take((size_t)NBOX * 4);
    u64* keysA = (u64*)take((size_t)NPAD * 8);
    float* tops = (float*)take((size_t)KPRE * 4);
    float* bx   = (float*)take((size_t)KPRE * 16);
    int*   lab  = (int*)take((size_t)KPRE * 4);
    float* obx  = (float*)take((size_t)KPRE * 16);
    u64* mask   = (u64*)take((size_t)KPRE * 32 * 8);
    float* fsc  = (float*)take((size_t)KPRE * 4);
    u64* keys2  = (u64*)take(2048 * 8);

    roi_pool_kernel<<<NPROP, 256, 0, stream>>>(feat, props, pooled);

    gemm_splitk<<<dim3(8, 4, S6), 256, 0, stream>>>(pooled, w6, partial, NPROP, KDIM, KDIM / S6);
    reduce_bias_relu<<<4000, 256, 0, stream>>>(partial, b6, h6, S6);

    gemm_splitk<<<dim3(8, 4, S6), 256, 0, stream>>>(h6, w7, partial, NPROP, HDIM, HDIM / S6);
    reduce_bias_relu<<<4000, 256, 0, stream>>>(partial, b7, h7, S6);

    heads_kernel<<<NPROP, 256, 0, stream>>>(h7, wcls, bcls, wreg, breg, cls, reg);

    decode_kernel<<<4, 256, 0, stream>>>(cls, reg, props, boxes_all, scores_all, keysA);

    sort_runs<<<10, 1024, 0, stream>>>(keysA);
    merge_all<<<1, 1024, 0, stream>>>(keysA, scores_all, boxes_all, tops, bx, lab, obx);

    iou_mask<<<KPRE, 64, 0, stream>>>(obx, mask);
    nms_scan_kernel<<<1, 64, 0, stream>>>(mask, tops, fsc, keys2);
    final_sort_out<<<1, 1024, 0, stream>>>(keys2, fsc, bx, lab, outp);
}